// Round 10
// baseline (92.434 us; speedup 1.0000x reference)
//
#include <hip/hip_runtime.h>
#include <math.h>

#define NQ 14
#define DIM (1 << NQ)      // 16384 amplitudes
#define NT 512             // 8 waves per block; 129 KB LDS -> 1 block/CU
#define TA 32              // amplitudes per thread (5-bit tile)
#define NW (NT / 64)

// ---- compile-time for ----
template <int J> struct IC { static constexpr int v = J; };
template <int N, typename F>
__device__ __forceinline__ void sfor(F&& f) {
    if constexpr (N > 0) { sfor<N - 1>(f); f(IC<N - 1>{}); }
}

// ---- state: 32 INDEPENDENT float2 SSA values (named members, compile-time
// indexed). r7 lesson: two v32f tuples force ~1400 pack/unpack movs and push
// pressure to ~145 regs -> spill at the allocator's hard 128 clamp. r8
// lesson: one 64-wide vector serializes the loads. Independent float2s give
// direct ds_read_b64 targets, free CNOT renames, minimal pressure. ----
struct St {
    float2 a0, a1, a2, a3, a4, a5, a6, a7, a8, a9, a10, a11, a12, a13, a14, a15,
           a16, a17, a18, a19, a20, a21, a22, a23, a24, a25, a26, a27, a28, a29, a30, a31;
};
template <int J> __device__ __forceinline__ float2& amp(St& s);
#define AMP_GET(J) template <> __device__ __forceinline__ float2& amp<J>(St& s) { return s.a##J; }
AMP_GET(0)  AMP_GET(1)  AMP_GET(2)  AMP_GET(3)  AMP_GET(4)  AMP_GET(5)  AMP_GET(6)  AMP_GET(7)
AMP_GET(8)  AMP_GET(9)  AMP_GET(10) AMP_GET(11) AMP_GET(12) AMP_GET(13) AMP_GET(14) AMP_GET(15)
AMP_GET(16) AMP_GET(17) AMP_GET(18) AMP_GET(19) AMP_GET(20) AMP_GET(21) AMP_GET(22) AMP_GET(23)
AMP_GET(24) AMP_GET(25) AMP_GET(26) AMP_GET(27) AMP_GET(28) AMP_GET(29) AMP_GET(30) AMP_GET(31)

// Bank swizzle on float2-index: phys = idx ^ ((idx>>5)&31). Linear under XOR.
// Verified: all four round tiles give each bank-pair exactly 4 lanes per
// unrolled j (the wave64 minimum) -> conflict-minimal b64.
__host__ __device__ constexpr int swz(int idx) { return idx ^ ((idx >> 5) & 31); }

// Tile over 5 bit positions: local bit k of j lives at global bit Pk.
// Non-tile bits get tid bits scattered ascending.
template <int P0, int P1, int P2, int P3, int P4>
struct Tile5 {
    static constexpr int PMASK = (1 << P0) | (1 << P1) | (1 << P2) | (1 << P3) | (1 << P4);
    static __device__ __forceinline__ int base_idx(int t) {
        int idx = 0, tb = 0;
#pragma unroll
        for (int p = 0; p < NQ; ++p)
            if (!((PMASK >> p) & 1)) { idx |= ((t >> tb) & 1) << p; ++tb; }
        return idx;
    }
    static constexpr int off(int j) {
        return ((j & 1) << P0) | (((j >> 1) & 1) << P1) | (((j >> 2) & 1) << P2) |
               (((j >> 3) & 1) << P3) | (((j >> 4) & 1) << P4);
    }
};

// qubit q lives at bit position 13-q.
using TileR1 = Tile5<9, 10, 11, 12, 13>;   // l4..l0 = q0,q1,q2,q3,q4
using TileR2 = Tile5<5, 6, 7, 8, 9>;       // l4..l0 = q4,q5,q6,q7,q8
using TileR3 = Tile5<1, 2, 3, 4, 5>;       // l4..l0 = q8,q9,q10,q11,q12
using TileR4 = Tile5<0, 1, 13, 12, 11>;    // l0=q13, l1=q12, l2=q0, l3=q1, l4=q2

template <class T>
__device__ __forceinline__ void load_tile(const float2* s, int pb, St& st) {
    sfor<TA>([&](auto jc) {
        constexpr int j = decltype(jc)::v;
        amp<j>(st) = s[pb ^ swz(T::off(j))];
    });
}
template <class T>
__device__ __forceinline__ void store_tile(float2* s, int pb, St& st) {
    sfor<TA>([&](auto jc) {
        constexpr int j = decltype(jc)::v;
        s[pb ^ swz(T::off(j))] = amp<j>(st);
    });
}

// RY: [[c,-s],[s,c]] — same op on both components (SLP-packable)
template <int LB>
__device__ __forceinline__ void g_ry(St& st, float c, float s) {
    sfor<TA>([&](auto jc) {
        constexpr int j = decltype(jc)::v;
        if constexpr (!(j & (1 << LB))) {
            constexpr int k = j | (1 << LB);
            float2 aj = amp<j>(st), ak = amp<k>(st), nj, nk;
            nj.x = c * aj.x - s * ak.x;  nj.y = c * aj.y - s * ak.y;
            nk.x = s * aj.x + c * ak.x;  nk.y = s * aj.y + c * ak.y;
            amp<j>(st) = nj; amp<k>(st) = nk;
        }
    });
}
// RX: [[c,-is],[-is,c]]
template <int LB>
__device__ __forceinline__ void g_rx(St& st, float c, float s) {
    sfor<TA>([&](auto jc) {
        constexpr int j = decltype(jc)::v;
        if constexpr (!(j & (1 << LB))) {
            constexpr int k = j | (1 << LB);
            float2 aj = amp<j>(st), ak = amp<k>(st), nj, nk;
            nj.x = c * aj.x + s * ak.y;  nj.y = c * aj.y - s * ak.x;
            nk.x = c * ak.x + s * aj.y;  nk.y = c * ak.y - s * aj.x;
            amp<j>(st) = nj; amp<k>(st) = nk;
        }
    });
}
// CNOT control local LC, target local LT: pure SSA rename (free)
template <int LC, int LT>
__device__ __forceinline__ void g_cnot(St& st) {
    sfor<TA>([&](auto jc) {
        constexpr int j = decltype(jc)::v;
        if constexpr (((j >> LC) & 1) && !((j >> LT) & 1)) {
            constexpr int k = j | (1 << LT);
            float2 t = amp<j>(st);
            amp<j>(st) = amp<k>(st);
            amp<k>(st) = t;
        }
    });
}

// Per layer, 4 rounds (ring CNOTs in order (q0,q1)..(q12,q13)(q13,q0)):
//  R1 {q0..q4}:  RX q0-4,  CNOT(q0,q1)(q1,q2)(q2,q3)(q3,q4)
//  R2 {q4..q8}:  RX q5-8,  CNOT(q4,q5)(q5,q6)(q6,q7)(q7,q8)
//  R3 {q8..q12}: RX q9-12, CNOT(q8,q9)(q9,q10)(q10,q11)(q11,q12)
//  R4 {q13,q12,q0,q1,q2}: RX q13, CNOT(q12,q13)(q13,q0)
// Embedding RYs folded into layer-0's rounds.
__global__ void __launch_bounds__(NT) qsim_kernel(const float* __restrict__ x,
                                                  const float* __restrict__ w,
                                                  float* __restrict__ out) {
    __shared__ float2 sSt[DIM];          // 128 KB
    __shared__ float sC[56], sS[56];     // [0..13]=RY embed, 14+l*14+q = RX
    __shared__ float sRed[NW][NQ];

    const int tid = threadIdx.x;
    const int b = blockIdx.x;

    if (tid < 14) {
        float th = tanhf(x[b * NQ + tid]) * 1.57079632679489662f;
        sC[tid] = cosf(th); sS[tid] = sinf(th);
    } else if (tid < 56) {
        float th = w[tid - 14] * 0.5f;
        sC[tid] = cosf(th); sS[tid] = sinf(th);
    }

    const int pb1 = swz(TileR1::base_idx(tid));
    const int pb2 = swz(TileR2::base_idx(tid));
    const int pb3 = swz(TileR3::base_idx(tid));
    const int pb4 = swz(TileR4::base_idx(tid));

    __syncthreads();

    St st;

    // ================= layer 0 (embedding folded in) =================
    {   // R1: init |0..0> + RY q0-4 + RX q0-4 + chain CNOTs
        sfor<TA>([&](auto jc) {
            constexpr int j = decltype(jc)::v;
            amp<j>(st) = make_float2(0.f, 0.f);
        });
        if (tid == 0) amp<0>(st).x = 1.f;
        g_ry<4>(st, sC[0], sS[0]);  g_ry<3>(st, sC[1], sS[1]);
        g_ry<2>(st, sC[2], sS[2]);  g_ry<1>(st, sC[3], sS[3]);
        g_ry<0>(st, sC[4], sS[4]);
        g_rx<4>(st, sC[14], sS[14]); g_rx<3>(st, sC[15], sS[15]);
        g_rx<2>(st, sC[16], sS[16]); g_rx<1>(st, sC[17], sS[17]);
        g_rx<0>(st, sC[18], sS[18]);
        g_cnot<4, 3>(st); g_cnot<3, 2>(st); g_cnot<2, 1>(st); g_cnot<1, 0>(st);
        store_tile<TileR1>(sSt, pb1, st);
    }
    __syncthreads();
    {   // R2: RY q5-8 + RX q5-8 + CNOT(q4,q5)..(q7,q8)
        load_tile<TileR2>(sSt, pb2, st);
        g_ry<3>(st, sC[5], sS[5]);  g_ry<2>(st, sC[6], sS[6]);
        g_ry<1>(st, sC[7], sS[7]);  g_ry<0>(st, sC[8], sS[8]);
        g_rx<3>(st, sC[19], sS[19]); g_rx<2>(st, sC[20], sS[20]);
        g_rx<1>(st, sC[21], sS[21]); g_rx<0>(st, sC[22], sS[22]);
        g_cnot<4, 3>(st); g_cnot<3, 2>(st); g_cnot<2, 1>(st); g_cnot<1, 0>(st);
        store_tile<TileR2>(sSt, pb2, st);
    }
    __syncthreads();
    {   // R3: RY q9-12 + RX q9-12 + CNOT(q8,q9)..(q11,q12)
        load_tile<TileR3>(sSt, pb3, st);
        g_ry<3>(st, sC[9], sS[9]);   g_ry<2>(st, sC[10], sS[10]);
        g_ry<1>(st, sC[11], sS[11]); g_ry<0>(st, sC[12], sS[12]);
        g_rx<3>(st, sC[23], sS[23]); g_rx<2>(st, sC[24], sS[24]);
        g_rx<1>(st, sC[25], sS[25]); g_rx<0>(st, sC[26], sS[26]);
        g_cnot<4, 3>(st); g_cnot<3, 2>(st); g_cnot<2, 1>(st); g_cnot<1, 0>(st);
        store_tile<TileR3>(sSt, pb3, st);
    }
    __syncthreads();
    {   // R4: RY q13 + RX q13 + CNOT(q12,q13)(q13,q0)
        load_tile<TileR4>(sSt, pb4, st);
        g_ry<0>(st, sC[13], sS[13]);
        g_rx<0>(st, sC[27], sS[27]);
        g_cnot<1, 0>(st); g_cnot<0, 2>(st);
        store_tile<TileR4>(sSt, pb4, st);
    }
    __syncthreads();

    // ================= layers 1,2 =================
#pragma unroll 1
    for (int l = 1; l < 3; ++l) {
        const int s0 = 14 + l * NQ;
        {   // R1
            load_tile<TileR1>(sSt, pb1, st);
            g_rx<4>(st, sC[s0 + 0], sS[s0 + 0]); g_rx<3>(st, sC[s0 + 1], sS[s0 + 1]);
            g_rx<2>(st, sC[s0 + 2], sS[s0 + 2]); g_rx<1>(st, sC[s0 + 3], sS[s0 + 3]);
            g_rx<0>(st, sC[s0 + 4], sS[s0 + 4]);
            g_cnot<4, 3>(st); g_cnot<3, 2>(st); g_cnot<2, 1>(st); g_cnot<1, 0>(st);
            store_tile<TileR1>(sSt, pb1, st);
        }
        __syncthreads();
        {   // R2
            load_tile<TileR2>(sSt, pb2, st);
            g_rx<3>(st, sC[s0 + 5], sS[s0 + 5]); g_rx<2>(st, sC[s0 + 6], sS[s0 + 6]);
            g_rx<1>(st, sC[s0 + 7], sS[s0 + 7]); g_rx<0>(st, sC[s0 + 8], sS[s0 + 8]);
            g_cnot<4, 3>(st); g_cnot<3, 2>(st); g_cnot<2, 1>(st); g_cnot<1, 0>(st);
            store_tile<TileR2>(sSt, pb2, st);
        }
        __syncthreads();
        {   // R3
            load_tile<TileR3>(sSt, pb3, st);
            g_rx<3>(st, sC[s0 + 9], sS[s0 + 9]);   g_rx<2>(st, sC[s0 + 10], sS[s0 + 10]);
            g_rx<1>(st, sC[s0 + 11], sS[s0 + 11]); g_rx<0>(st, sC[s0 + 12], sS[s0 + 12]);
            g_cnot<4, 3>(st); g_cnot<3, 2>(st); g_cnot<2, 1>(st); g_cnot<1, 0>(st);
            store_tile<TileR3>(sSt, pb3, st);
        }
        __syncthreads();
        {   // R4
            load_tile<TileR4>(sSt, pb4, st);
            g_rx<0>(st, sC[s0 + 13], sS[s0 + 13]);
            g_cnot<1, 0>(st); g_cnot<0, 2>(st);
            if (l == 1) store_tile<TileR4>(sSt, pb4, st);
        }
        if (l == 1) __syncthreads();
    }

    // ====== expvals from final registers (TileR4: l0=q13,l1=q12,l2=q0,l3=q1,l4=q2) ======
    float Stot = 0.f, S0 = 0.f, S1 = 0.f, S2 = 0.f, S3 = 0.f, S4 = 0.f;
    sfor<TA>([&](auto jc) {
        constexpr int j = decltype(jc)::v;
        float2 v = amp<j>(st);
        float pj = v.x * v.x + v.y * v.y;
        Stot += pj;
        S0 += (j & 1)  ? -pj : pj;   // q13
        S1 += (j & 2)  ? -pj : pj;   // q12
        S2 += (j & 4)  ? -pj : pj;   // q0
        S3 += (j & 8)  ? -pj : pj;   // q1
        S4 += (j & 16) ? -pj : pj;   // q2
    });
    float ev[NQ];
    ev[0] = S2; ev[1] = S3; ev[2] = S4; ev[12] = S1; ev[13] = S0;
#pragma unroll
    for (int q = 3; q <= 11; ++q)    // q3..q11 <- tid bit (11-q)
        ev[q] = ((tid >> (11 - q)) & 1) ? -Stot : Stot;

#pragma unroll
    for (int q = 0; q < NQ; ++q) {
#pragma unroll
        for (int o = 32; o > 0; o >>= 1) ev[q] += __shfl_down(ev[q], o);
    }
    const int wv = tid >> 6, ln = tid & 63;
    if (ln == 0) {
#pragma unroll
        for (int q = 0; q < NQ; ++q) sRed[wv][q] = ev[q];
    }
    __syncthreads();
    if (tid < NQ) {
        float acc = 0.f;
#pragma unroll
        for (int k = 0; k < NW; ++k) acc += sRed[k][tid];
        out[b * NQ + tid] = acc;
    }
}

extern "C" void kernel_launch(void* const* d_in, const int* in_sizes, int n_in,
                              void* d_out, int out_size, void* d_ws, size_t ws_size,
                              hipStream_t stream) {
    const float* x = (const float*)d_in[0];   // (256, 14) float32
    const float* w = (const float*)d_in[1];   // (3, 14) float32
    float* out = (float*)d_out;               // (256, 14) float32
    qsim_kernel<<<256, NT, 0, stream>>>(x, w, out);
}

// Round 11
// 86.819 us; speedup vs baseline: 1.0647x; 1.0647x over previous
//
#include <hip/hip_runtime.h>
#include <math.h>

#define NQ 14
#define DIM (1 << NQ)      // 16384 amplitudes
#define NT 512             // 8 waves per block; ~133 KB LDS -> 1 block/CU
#define TA 32              // amplitudes per thread (5-bit tile)
#define NW (NT / 64)
#define PDIM (DIM + DIM / 32)   // padded: one spare float2 per 32

// ---- compile-time for ----
template <int J> struct IC { static constexpr int v = J; };
template <int N, typename F>
__device__ __forceinline__ void sfor(F&& f) {
    if constexpr (N > 0) { sfor<N - 1>(f); f(IC<N - 1>{}); }
}

// ---- state: 32 independent float2 SSA values (compile-time indexed).
// ds_read_b64 lands directly in each pair; CNOT = free rename. ----
struct St {
    float2 a0, a1, a2, a3, a4, a5, a6, a7, a8, a9, a10, a11, a12, a13, a14, a15,
           a16, a17, a18, a19, a20, a21, a22, a23, a24, a25, a26, a27, a28, a29, a30, a31;
};
template <int J> __device__ __forceinline__ float2& amp(St& s);
#define AMP_GET(J) template <> __device__ __forceinline__ float2& amp<J>(St& s) { return s.a##J; }
AMP_GET(0)  AMP_GET(1)  AMP_GET(2)  AMP_GET(3)  AMP_GET(4)  AMP_GET(5)  AMP_GET(6)  AMP_GET(7)
AMP_GET(8)  AMP_GET(9)  AMP_GET(10) AMP_GET(11) AMP_GET(12) AMP_GET(13) AMP_GET(14) AMP_GET(15)
AMP_GET(16) AMP_GET(17) AMP_GET(18) AMP_GET(19) AMP_GET(20) AMP_GET(21) AMP_GET(22) AMP_GET(23)
AMP_GET(24) AMP_GET(25) AMP_GET(26) AMP_GET(27) AMP_GET(28) AMP_GET(29) AMP_GET(30) AMP_GET(31)

// ---- additive padded layout (replaces the XOR swizzle; r10 lesson: XOR
// addressing keeps 32 computed addresses live per sweep -> spill at the hard
// 128-VGPR clamp). phys(idx) = idx + (idx>>5). Tile base bits and offset bits
// are disjoint (no carries), so phys(base+off) = phys(base) + phys(off):
// every LDS access is base + compile-time const -> ds immediate offset.
// Bank check (all 4 tiles): phys(base(tid)) mod 32 covers all 32 bank-pairs
// exactly 2 lanes each -> conflict-free b64. ----
__host__ __device__ constexpr int pad(int idx) { return idx + (idx >> 5); }

// Tile over 5 bit positions: local bit k of j lives at global bit Pk.
// Non-tile bits get tid bits scattered ascending.
template <int P0, int P1, int P2, int P3, int P4>
struct Tile5 {
    static constexpr int PMASK = (1 << P0) | (1 << P1) | (1 << P2) | (1 << P3) | (1 << P4);
    static __device__ __forceinline__ int base_idx(int t) {
        int idx = 0, tb = 0;
#pragma unroll
        for (int p = 0; p < NQ; ++p)
            if (!((PMASK >> p) & 1)) { idx |= ((t >> tb) & 1) << p; ++tb; }
        return idx;
    }
    static constexpr int off(int j) {
        return ((j & 1) << P0) | (((j >> 1) & 1) << P1) | (((j >> 2) & 1) << P2) |
               (((j >> 3) & 1) << P3) | (((j >> 4) & 1) << P4);
    }
    static constexpr int poff(int j) { return pad(off(j)); }
};

// qubit q lives at bit position 13-q.
using TileR1 = Tile5<9, 10, 11, 12, 13>;   // l4..l0 = q0,q1,q2,q3,q4
using TileR2 = Tile5<5, 6, 7, 8, 9>;       // l4..l0 = q4,q5,q6,q7,q8
using TileR3 = Tile5<1, 2, 3, 4, 5>;       // l4..l0 = q8,q9,q10,q11,q12
using TileR4 = Tile5<0, 1, 13, 12, 11>;    // l0=q13, l1=q12, l2=q0, l3=q1, l4=q2

template <class T>
__device__ __forceinline__ void load_tile(const float2* s, int pb, St& st) {
    sfor<TA>([&](auto jc) {
        constexpr int j = decltype(jc)::v;
        amp<j>(st) = s[pb + T::poff(j)];
    });
}
template <class T>
__device__ __forceinline__ void store_tile(float2* s, int pb, St& st) {
    sfor<TA>([&](auto jc) {
        constexpr int j = decltype(jc)::v;
        s[pb + T::poff(j)] = amp<j>(st);
    });
}

// RY: [[c,-s],[s,c]]
template <int LB>
__device__ __forceinline__ void g_ry(St& st, float c, float s) {
    sfor<TA>([&](auto jc) {
        constexpr int j = decltype(jc)::v;
        if constexpr (!(j & (1 << LB))) {
            constexpr int k = j | (1 << LB);
            float2 aj = amp<j>(st), ak = amp<k>(st), nj, nk;
            nj.x = c * aj.x - s * ak.x;  nj.y = c * aj.y - s * ak.y;
            nk.x = s * aj.x + c * ak.x;  nk.y = s * aj.y + c * ak.y;
            amp<j>(st) = nj; amp<k>(st) = nk;
        }
    });
}
// RX: [[c,-is],[-is,c]]
template <int LB>
__device__ __forceinline__ void g_rx(St& st, float c, float s) {
    sfor<TA>([&](auto jc) {
        constexpr int j = decltype(jc)::v;
        if constexpr (!(j & (1 << LB))) {
            constexpr int k = j | (1 << LB);
            float2 aj = amp<j>(st), ak = amp<k>(st), nj, nk;
            nj.x = c * aj.x + s * ak.y;  nj.y = c * aj.y - s * ak.x;
            nk.x = c * ak.x + s * aj.y;  nk.y = c * ak.y - s * aj.x;
            amp<j>(st) = nj; amp<k>(st) = nk;
        }
    });
}
// CNOT control local LC, target local LT: pure SSA rename (free)
template <int LC, int LT>
__device__ __forceinline__ void g_cnot(St& st) {
    sfor<TA>([&](auto jc) {
        constexpr int j = decltype(jc)::v;
        if constexpr (((j >> LC) & 1) && !((j >> LT) & 1)) {
            constexpr int k = j | (1 << LT);
            float2 t = amp<j>(st);
            amp<j>(st) = amp<k>(st);
            amp<k>(st) = t;
        }
    });
}

// Per layer, 4 rounds (ring CNOTs in order (q0,q1)..(q12,q13)(q13,q0)):
//  R1 {q0..q4}:  RX q0-4,  CNOT(q0,q1)(q1,q2)(q2,q3)(q3,q4)
//  R2 {q4..q8}:  RX q5-8,  CNOT(q4,q5)(q5,q6)(q6,q7)(q7,q8)
//  R3 {q8..q12}: RX q9-12, CNOT(q8,q9)(q9,q10)(q10,q11)(q11,q12)
//  R4 {q13,q12,q0,q1,q2}: RX q13, CNOT(q12,q13)(q13,q0)
// Embedding RYs folded into layer-0's rounds.
__global__ void __launch_bounds__(NT) qsim_kernel(const float* __restrict__ x,
                                                  const float* __restrict__ w,
                                                  float* __restrict__ out) {
    __shared__ float2 sSt[PDIM];         // ~132 KB padded
    __shared__ float sC[56], sS[56];     // [0..13]=RY embed, 14+l*14+q = RX
    __shared__ float sRed[NW][NQ];

    const int tid = threadIdx.x;
    const int b = blockIdx.x;

    if (tid < 14) {
        float th = tanhf(x[b * NQ + tid]) * 1.57079632679489662f;
        sC[tid] = cosf(th); sS[tid] = sinf(th);
    } else if (tid < 56) {
        float th = w[tid - 14] * 0.5f;
        sC[tid] = cosf(th); sS[tid] = sinf(th);
    }

    const int pb1 = pad(TileR1::base_idx(tid));
    const int pb2 = pad(TileR2::base_idx(tid));
    const int pb3 = pad(TileR3::base_idx(tid));
    const int pb4 = pad(TileR4::base_idx(tid));

    __syncthreads();

    St st;

    // ================= layer 0 (embedding folded in) =================
    {   // R1: init |0..0> + RY q0-4 + RX q0-4 + chain CNOTs
        sfor<TA>([&](auto jc) {
            constexpr int j = decltype(jc)::v;
            amp<j>(st) = make_float2(0.f, 0.f);
        });
        if (tid == 0) amp<0>(st).x = 1.f;
        g_ry<4>(st, sC[0], sS[0]);  g_ry<3>(st, sC[1], sS[1]);
        g_ry<2>(st, sC[2], sS[2]);  g_ry<1>(st, sC[3], sS[3]);
        g_ry<0>(st, sC[4], sS[4]);
        g_rx<4>(st, sC[14], sS[14]); g_rx<3>(st, sC[15], sS[15]);
        g_rx<2>(st, sC[16], sS[16]); g_rx<1>(st, sC[17], sS[17]);
        g_rx<0>(st, sC[18], sS[18]);
        g_cnot<4, 3>(st); g_cnot<3, 2>(st); g_cnot<2, 1>(st); g_cnot<1, 0>(st);
        store_tile<TileR1>(sSt, pb1, st);
    }
    __syncthreads();
    {   // R2: RY q5-8 + RX q5-8 + CNOT(q4,q5)..(q7,q8)
        load_tile<TileR2>(sSt, pb2, st);
        g_ry<3>(st, sC[5], sS[5]);  g_ry<2>(st, sC[6], sS[6]);
        g_ry<1>(st, sC[7], sS[7]);  g_ry<0>(st, sC[8], sS[8]);
        g_rx<3>(st, sC[19], sS[19]); g_rx<2>(st, sC[20], sS[20]);
        g_rx<1>(st, sC[21], sS[21]); g_rx<0>(st, sC[22], sS[22]);
        g_cnot<4, 3>(st); g_cnot<3, 2>(st); g_cnot<2, 1>(st); g_cnot<1, 0>(st);
        store_tile<TileR2>(sSt, pb2, st);
    }
    __syncthreads();
    {   // R3: RY q9-12 + RX q9-12 + CNOT(q8,q9)..(q11,q12)
        load_tile<TileR3>(sSt, pb3, st);
        g_ry<3>(st, sC[9], sS[9]);   g_ry<2>(st, sC[10], sS[10]);
        g_ry<1>(st, sC[11], sS[11]); g_ry<0>(st, sC[12], sS[12]);
        g_rx<3>(st, sC[23], sS[23]); g_rx<2>(st, sC[24], sS[24]);
        g_rx<1>(st, sC[25], sS[25]); g_rx<0>(st, sC[26], sS[26]);
        g_cnot<4, 3>(st); g_cnot<3, 2>(st); g_cnot<2, 1>(st); g_cnot<1, 0>(st);
        store_tile<TileR3>(sSt, pb3, st);
    }
    __syncthreads();
    {   // R4: RY q13 + RX q13 + CNOT(q12,q13)(q13,q0)
        load_tile<TileR4>(sSt, pb4, st);
        g_ry<0>(st, sC[13], sS[13]);
        g_rx<0>(st, sC[27], sS[27]);
        g_cnot<1, 0>(st); g_cnot<0, 2>(st);
        store_tile<TileR4>(sSt, pb4, st);
    }
    __syncthreads();

    // ================= layers 1,2 =================
#pragma unroll 1
    for (int l = 1; l < 3; ++l) {
        const int s0 = 14 + l * NQ;
        {   // R1
            load_tile<TileR1>(sSt, pb1, st);
            g_rx<4>(st, sC[s0 + 0], sS[s0 + 0]); g_rx<3>(st, sC[s0 + 1], sS[s0 + 1]);
            g_rx<2>(st, sC[s0 + 2], sS[s0 + 2]); g_rx<1>(st, sC[s0 + 3], sS[s0 + 3]);
            g_rx<0>(st, sC[s0 + 4], sS[s0 + 4]);
            g_cnot<4, 3>(st); g_cnot<3, 2>(st); g_cnot<2, 1>(st); g_cnot<1, 0>(st);
            store_tile<TileR1>(sSt, pb1, st);
        }
        __syncthreads();
        {   // R2
            load_tile<TileR2>(sSt, pb2, st);
            g_rx<3>(st, sC[s0 + 5], sS[s0 + 5]); g_rx<2>(st, sC[s0 + 6], sS[s0 + 6]);
            g_rx<1>(st, sC[s0 + 7], sS[s0 + 7]); g_rx<0>(st, sC[s0 + 8], sS[s0 + 8]);
            g_cnot<4, 3>(st); g_cnot<3, 2>(st); g_cnot<2, 1>(st); g_cnot<1, 0>(st);
            store_tile<TileR2>(sSt, pb2, st);
        }
        __syncthreads();
        {   // R3
            load_tile<TileR3>(sSt, pb3, st);
            g_rx<3>(st, sC[s0 + 9], sS[s0 + 9]);   g_rx<2>(st, sC[s0 + 10], sS[s0 + 10]);
            g_rx<1>(st, sC[s0 + 11], sS[s0 + 11]); g_rx<0>(st, sC[s0 + 12], sS[s0 + 12]);
            g_cnot<4, 3>(st); g_cnot<3, 2>(st); g_cnot<2, 1>(st); g_cnot<1, 0>(st);
            store_tile<TileR3>(sSt, pb3, st);
        }
        __syncthreads();
        {   // R4
            load_tile<TileR4>(sSt, pb4, st);
            g_rx<0>(st, sC[s0 + 13], sS[s0 + 13]);
            g_cnot<1, 0>(st); g_cnot<0, 2>(st);
            if (l == 1) store_tile<TileR4>(sSt, pb4, st);
        }
        if (l == 1) __syncthreads();
    }

    // ====== expvals from final registers (TileR4: l0=q13,l1=q12,l2=q0,l3=q1,l4=q2) ======
    float Stot = 0.f, S0 = 0.f, S1 = 0.f, S2 = 0.f, S3 = 0.f, S4 = 0.f;
    sfor<TA>([&](auto jc) {
        constexpr int j = decltype(jc)::v;
        float2 v = amp<j>(st);
        float pj = v.x * v.x + v.y * v.y;
        Stot += pj;
        S0 += (j & 1)  ? -pj : pj;   // q13
        S1 += (j & 2)  ? -pj : pj;   // q12
        S2 += (j & 4)  ? -pj : pj;   // q0
        S3 += (j & 8)  ? -pj : pj;   // q1
        S4 += (j & 16) ? -pj : pj;   // q2
    });
    float ev[NQ];
    ev[0] = S2; ev[1] = S3; ev[2] = S4; ev[12] = S1; ev[13] = S0;
#pragma unroll
    for (int q = 3; q <= 11; ++q)    // q3..q11 <- tid bit (11-q)
        ev[q] = ((tid >> (11 - q)) & 1) ? -Stot : Stot;

#pragma unroll
    for (int q = 0; q < NQ; ++q) {
#pragma unroll
        for (int o = 32; o > 0; o >>= 1) ev[q] += __shfl_down(ev[q], o);
    }
    const int wv = tid >> 6, ln = tid & 63;
    if (ln == 0) {
#pragma unroll
        for (int q = 0; q < NQ; ++q) sRed[wv][q] = ev[q];
    }
    __syncthreads();
    if (tid < NQ) {
        float acc = 0.f;
#pragma unroll
        for (int k = 0; k < NW; ++k) acc += sRed[k][tid];
        out[b * NQ + tid] = acc;
    }
}

extern "C" void kernel_launch(void* const* d_in, const int* in_sizes, int n_in,
                              void* d_out, int out_size, void* d_ws, size_t ws_size,
                              hipStream_t stream) {
    const float* x = (const float*)d_in[0];   // (256, 14) float32
    const float* w = (const float*)d_in[1];   // (3, 14) float32
    float* out = (float*)d_out;               // (256, 14) float32
    qsim_kernel<<<256, NT, 0, stream>>>(x, w, out);
}